// Round 5
// baseline (116.203 us; speedup 1.0000x reference)
//
#include <hip/hip_runtime.h>

// DeepFilter: P_r = xr*fr - xi*fi, P_i = 2*xr*fi (elementwise, same location),
// out = 3x5 zero-padded box sum of P over (freq d, time t).
// Memory-bound: 64 MiB in + 32 MiB out => ~16 us floor at 6.3 TB/s.
//
// R5 = R2 tiling (TTILE=128, best measured) + NT output stores from R4.
// Isolates the NT-store variable; R4's TTILE=256 is reverted (112.8 -> 114.6
// regression, noise-level but the 128 tile was never beaten).

#define BB 8
#define DD 256
#define TT_FULL 2048
#define DTILE 8
#define TTILE 128
#define RROWS (DTILE + 2)      // 10
#define RCOLS4 34              // float4s per halo row (cols t0-4 .. t0+131)
#define LSTRIDE 136            // floats per LDS row (= RCOLS4*4, 16B-aligned)

typedef float floatx4 __attribute__((ext_vector_type(4)));

__global__ __launch_bounds__(256) void deepfilter_kernel(
    const float* __restrict__ xr, const float* __restrict__ xi,
    const float* __restrict__ fr, const float* __restrict__ fi,
    float* __restrict__ out)
{
    __shared__ float Pr[RROWS][LSTRIDE];
    __shared__ float Pi[RROWS][LSTRIDE];

    const int tt  = blockIdx.x;        // 0..15  time tile
    const int dt  = blockIdx.y;        // 0..31  freq tile
    const int b   = blockIdx.z;        // 0..7   batch
    const int t0  = tt * TTILE;
    const int d0  = dt * DTILE;
    const int tid = threadIdx.x;

    const size_t base_in = (size_t)b * DD * TT_FULL;

    // ---- Phase 1: P over halo rows d0-1..d0+8, cols t0-4..t0+131 (float4s)
    #pragma unroll
    for (int k = 0; k < 2; ++k) {
        const int idx = tid + k * 256;
        if (idx < RROWS * RCOLS4) {
            const int row = idx / RCOLS4;
            const int c4  = idx - row * RCOLS4;
            const int d   = d0 + row - 1;
            const int tg  = t0 - 4 + (c4 << 2);   // global t of float4 start
            float4 pr4 = {0.f, 0.f, 0.f, 0.f};
            float4 pi4 = {0.f, 0.f, 0.f, 0.f};
            if ((unsigned)d < (unsigned)DD) {
                const size_t roff = base_in + (size_t)d * TT_FULL;
                float4 r4, i4, g4, h4;
                if (tg >= 0 && tg <= TT_FULL - 4) {
                    r4 = *(const float4*)(xr + roff + tg);
                    i4 = *(const float4*)(xi + roff + tg);
                    g4 = *(const float4*)(fr + roff + tg);
                    h4 = *(const float4*)(fi + roff + tg);
                } else {
                    float rr[4], ii[4], gg[4], hh[4];
                    #pragma unroll
                    for (int j = 0; j < 4; ++j) {
                        const int t = tg + j;
                        const bool ok = (unsigned)t < (unsigned)TT_FULL;
                        rr[j] = ok ? xr[roff + t] : 0.f;
                        ii[j] = ok ? xi[roff + t] : 0.f;
                        gg[j] = ok ? fr[roff + t] : 0.f;
                        hh[j] = ok ? fi[roff + t] : 0.f;
                    }
                    r4 = make_float4(rr[0], rr[1], rr[2], rr[3]);
                    i4 = make_float4(ii[0], ii[1], ii[2], ii[3]);
                    g4 = make_float4(gg[0], gg[1], gg[2], gg[3]);
                    h4 = make_float4(hh[0], hh[1], hh[2], hh[3]);
                }
                pr4.x = r4.x * g4.x - i4.x * h4.x;
                pr4.y = r4.y * g4.y - i4.y * h4.y;
                pr4.z = r4.z * g4.z - i4.z * h4.z;
                pr4.w = r4.w * g4.w - i4.w * h4.w;
                pi4.x = 2.f * r4.x * h4.x;
                pi4.y = 2.f * r4.y * h4.y;
                pi4.z = 2.f * r4.z * h4.z;
                pi4.w = 2.f * r4.w * h4.w;
            }
            *(float4*)&Pr[row][c4 << 2] = pr4;
            *(float4*)&Pi[row][c4 << 2] = pi4;
        }
    }
    __syncthreads();

    // ---- Phase 2: thread -> 4 consecutive output cols of one output row.
    // LDS col l holds global t = t0 - 4 + l; output col c uses window
    // l = c+2 .. c+6.
    const int orow = tid >> 5;           // 0..7
    const int oc   = (tid & 31) << 2;    // 0,4,..,124 (16B-aligned)

    float4 Ar = {0,0,0,0}, Br = {0,0,0,0};
    float2 Cr = {0,0};
    float4 Ai = {0,0,0,0}, Bi = {0,0,0,0};
    float2 Ci = {0,0};
    #pragma unroll
    for (int kf = 0; kf < 3; ++kf) {
        const float* rp = &Pr[orow + kf][oc];
        const float* ip = &Pi[orow + kf][oc];
        float4 v0 = *(const float4*)rp;          // cols oc   .. oc+3
        float4 v1 = *(const float4*)(rp + 4);    // cols oc+4 .. oc+7
        float2 v2 = *(const float2*)(rp + 8);    // cols oc+8 .. oc+9
        Ar.x += v0.x; Ar.y += v0.y; Ar.z += v0.z; Ar.w += v0.w;
        Br.x += v1.x; Br.y += v1.y; Br.z += v1.z; Br.w += v1.w;
        Cr.x += v2.x; Cr.y += v2.y;
        float4 w0 = *(const float4*)ip;
        float4 w1 = *(const float4*)(ip + 4);
        float2 w2 = *(const float2*)(ip + 8);
        Ai.x += w0.x; Ai.y += w0.y; Ai.z += w0.z; Ai.w += w0.w;
        Bi.x += w1.x; Bi.y += w1.y; Bi.z += w1.z; Bi.w += w1.w;
        Ci.x += w2.x; Ci.y += w2.y;
    }

    // s[i] = 3-row column sum at LDS col oc+2+i ; out[j] = sum s[j..j+4]
    floatx4 outr, outi;
    {
        const float s0 = Ar.z, s1 = Ar.w, s2 = Br.x, s3 = Br.y,
                    s4 = Br.z, s5 = Br.w, s6 = Cr.x, s7 = Cr.y;
        const float m = s3 + s4;
        const float a = s1 + s2 + m;
        const float bmid = s2 + m + s5;
        outr.x = s0 + a;
        outr.y = a + s5;
        outr.z = bmid + s6;
        outr.w = m + s5 + s6 + s7;
    }
    {
        const float s0 = Ai.z, s1 = Ai.w, s2 = Bi.x, s3 = Bi.y,
                    s4 = Bi.z, s5 = Bi.w, s6 = Ci.x, s7 = Ci.y;
        const float m = s3 + s4;
        const float a = s1 + s2 + m;
        const float bmid = s2 + m + s5;
        outi.x = s0 + a;
        outi.y = a + s5;
        outi.z = bmid + s6;
        outi.w = m + s5 + s6 + s7;
    }

    const size_t obase = (size_t)b * (2 * DD * TT_FULL)
                       + (size_t)(d0 + orow) * TT_FULL + (t0 + oc);
    floatx4* pr_out = (floatx4*)&out[obase];
    floatx4* pi_out = (floatx4*)&out[obase + (size_t)DD * TT_FULL];
    __builtin_nontemporal_store(outr, pr_out);   // write-once: bypass L2
    __builtin_nontemporal_store(outi, pi_out);
}

extern "C" void kernel_launch(void* const* d_in, const int* in_sizes, int n_in,
                              void* d_out, int out_size, void* d_ws, size_t ws_size,
                              hipStream_t stream) {
    const float* xr = (const float*)d_in[0];
    const float* xi = (const float*)d_in[1];
    const float* fr = (const float*)d_in[2];
    const float* fi = (const float*)d_in[3];
    float* out = (float*)d_out;

    dim3 grid(TT_FULL / TTILE, DD / DTILE, BB);  // (16, 32, 8) = 4096 blocks
    deepfilter_kernel<<<grid, 256, 0, stream>>>(xr, xi, fr, fi, out);
}

// Round 6
// 112.783 us; speedup vs baseline: 1.0303x; 1.0303x over previous
//
#include <hip/hip_runtime.h>

// DeepFilter: P_r = xr*fr - xi*fi, P_i = 2*xr*fi (elementwise, same location),
// out = 3x5 zero-padded box sum of P over (freq d, time t).
// Memory-bound: 64 MiB in + 32 MiB out => ~16 us floor at 6.3 TB/s.
//
// R6 = exact R2 (best measured: 112.8 us bench). Reverts the two tested
// hypotheses that regressed:
//   - TTILE=256 (R4, +1.8 us): halo reduction immaterial, L2 absorbs re-reads
//   - NT output stores (R4/R5, +2-3 us both times): output stream does not
//     contend with input reuse in L2; NT slightly hurts write path.
// Kernel itself is <41 us (never appears in rocprof top-5; harness 268 MB
// poison fills at ~6.4 TB/s dominate bench dur_us). Estimated kernel time
// ~20-25 us vs 16 us HBM floor; residual headroom is below bench noise.

#define BB 8
#define DD 256
#define TT_FULL 2048
#define DTILE 8
#define TTILE 128
#define RROWS (DTILE + 2)      // 10
#define RCOLS4 34              // float4s per halo row (cols t0-4 .. t0+131)
#define LSTRIDE 136            // floats per LDS row (= RCOLS4*4, 16B-aligned)

__global__ __launch_bounds__(256) void deepfilter_kernel(
    const float* __restrict__ xr, const float* __restrict__ xi,
    const float* __restrict__ fr, const float* __restrict__ fi,
    float* __restrict__ out)
{
    __shared__ float Pr[RROWS][LSTRIDE];
    __shared__ float Pi[RROWS][LSTRIDE];

    const int tt  = blockIdx.x;        // 0..15  time tile
    const int dt  = blockIdx.y;        // 0..31  freq tile
    const int b   = blockIdx.z;        // 0..7   batch
    const int t0  = tt * TTILE;
    const int d0  = dt * DTILE;
    const int tid = threadIdx.x;

    const size_t base_in = (size_t)b * DD * TT_FULL;

    // ---- Phase 1: P over halo rows d0-1..d0+8, cols t0-4..t0+131 (float4s)
    #pragma unroll
    for (int k = 0; k < 2; ++k) {
        const int idx = tid + k * 256;
        if (idx < RROWS * RCOLS4) {
            const int row = idx / RCOLS4;
            const int c4  = idx - row * RCOLS4;
            const int d   = d0 + row - 1;
            const int tg  = t0 - 4 + (c4 << 2);   // global t of float4 start
            float4 pr4 = {0.f, 0.f, 0.f, 0.f};
            float4 pi4 = {0.f, 0.f, 0.f, 0.f};
            if ((unsigned)d < (unsigned)DD) {
                const size_t roff = base_in + (size_t)d * TT_FULL;
                float4 r4, i4, g4, h4;
                if (tg >= 0 && tg <= TT_FULL - 4) {
                    r4 = *(const float4*)(xr + roff + tg);
                    i4 = *(const float4*)(xi + roff + tg);
                    g4 = *(const float4*)(fr + roff + tg);
                    h4 = *(const float4*)(fi + roff + tg);
                } else {
                    float rr[4], ii[4], gg[4], hh[4];
                    #pragma unroll
                    for (int j = 0; j < 4; ++j) {
                        const int t = tg + j;
                        const bool ok = (unsigned)t < (unsigned)TT_FULL;
                        rr[j] = ok ? xr[roff + t] : 0.f;
                        ii[j] = ok ? xi[roff + t] : 0.f;
                        gg[j] = ok ? fr[roff + t] : 0.f;
                        hh[j] = ok ? fi[roff + t] : 0.f;
                    }
                    r4 = make_float4(rr[0], rr[1], rr[2], rr[3]);
                    i4 = make_float4(ii[0], ii[1], ii[2], ii[3]);
                    g4 = make_float4(gg[0], gg[1], gg[2], gg[3]);
                    h4 = make_float4(hh[0], hh[1], hh[2], hh[3]);
                }
                pr4.x = r4.x * g4.x - i4.x * h4.x;
                pr4.y = r4.y * g4.y - i4.y * h4.y;
                pr4.z = r4.z * g4.z - i4.z * h4.z;
                pr4.w = r4.w * g4.w - i4.w * h4.w;
                pi4.x = 2.f * r4.x * h4.x;
                pi4.y = 2.f * r4.y * h4.y;
                pi4.z = 2.f * r4.z * h4.z;
                pi4.w = 2.f * r4.w * h4.w;
            }
            *(float4*)&Pr[row][c4 << 2] = pr4;
            *(float4*)&Pi[row][c4 << 2] = pi4;
        }
    }
    __syncthreads();

    // ---- Phase 2: thread -> 4 consecutive output cols of one output row.
    // LDS col l holds global t = t0 - 4 + l; output col c uses window
    // l = c+2 .. c+6.
    const int orow = tid >> 5;           // 0..7
    const int oc   = (tid & 31) << 2;    // 0,4,..,124 (16B-aligned)

    float4 Ar = {0,0,0,0}, Br = {0,0,0,0};
    float2 Cr = {0,0};
    float4 Ai = {0,0,0,0}, Bi = {0,0,0,0};
    float2 Ci = {0,0};
    #pragma unroll
    for (int kf = 0; kf < 3; ++kf) {
        const float* rp = &Pr[orow + kf][oc];
        const float* ip = &Pi[orow + kf][oc];
        float4 v0 = *(const float4*)rp;          // cols oc   .. oc+3
        float4 v1 = *(const float4*)(rp + 4);    // cols oc+4 .. oc+7
        float2 v2 = *(const float2*)(rp + 8);    // cols oc+8 .. oc+9
        Ar.x += v0.x; Ar.y += v0.y; Ar.z += v0.z; Ar.w += v0.w;
        Br.x += v1.x; Br.y += v1.y; Br.z += v1.z; Br.w += v1.w;
        Cr.x += v2.x; Cr.y += v2.y;
        float4 w0 = *(const float4*)ip;
        float4 w1 = *(const float4*)(ip + 4);
        float2 w2 = *(const float2*)(ip + 8);
        Ai.x += w0.x; Ai.y += w0.y; Ai.z += w0.z; Ai.w += w0.w;
        Bi.x += w1.x; Bi.y += w1.y; Bi.z += w1.z; Bi.w += w1.w;
        Ci.x += w2.x; Ci.y += w2.y;
    }

    // s[i] = 3-row column sum at LDS col oc+2+i ; out[j] = sum s[j..j+4]
    float4 outr, outi;
    {
        const float s0 = Ar.z, s1 = Ar.w, s2 = Br.x, s3 = Br.y,
                    s4 = Br.z, s5 = Br.w, s6 = Cr.x, s7 = Cr.y;
        const float m = s3 + s4;
        const float a = s1 + s2 + m;
        const float bmid = s2 + m + s5;
        outr.x = s0 + a;
        outr.y = a + s5;
        outr.z = bmid + s6;
        outr.w = m + s5 + s6 + s7;
    }
    {
        const float s0 = Ai.z, s1 = Ai.w, s2 = Bi.x, s3 = Bi.y,
                    s4 = Bi.z, s5 = Bi.w, s6 = Ci.x, s7 = Ci.y;
        const float m = s3 + s4;
        const float a = s1 + s2 + m;
        const float bmid = s2 + m + s5;
        outi.x = s0 + a;
        outi.y = a + s5;
        outi.z = bmid + s6;
        outi.w = m + s5 + s6 + s7;
    }

    const size_t obase = (size_t)b * (2 * DD * TT_FULL)
                       + (size_t)(d0 + orow) * TT_FULL + (t0 + oc);
    *(float4*)&out[obase] = outr;                              // real half
    *(float4*)&out[obase + (size_t)DD * TT_FULL] = outi;       // imag half
}

extern "C" void kernel_launch(void* const* d_in, const int* in_sizes, int n_in,
                              void* d_out, int out_size, void* d_ws, size_t ws_size,
                              hipStream_t stream) {
    const float* xr = (const float*)d_in[0];
    const float* xi = (const float*)d_in[1];
    const float* fr = (const float*)d_in[2];
    const float* fi = (const float*)d_in[3];
    float* out = (float*)d_out;

    dim3 grid(TT_FULL / TTILE, DD / DTILE, BB);  // (16, 32, 8) = 4096 blocks
    deepfilter_kernel<<<grid, 256, 0, stream>>>(xr, xi, fr, fi, out);
}